// Round 1
// baseline (121.454 us; speedup 1.0000x reference)
//
#include <hip/hip_runtime.h>
#include <math.h>

// DegreeQuantileConverter:
//   deg: (B,S,1) f32, q: (12,) f32 = [0,1,2,4,...,1024]
//   out: (B,S,12) f32 = log(w + 1e-30) where w is the linear-interp 2-hot row
//   (idx from searchsorted-right minus 1, clipped to [0,10]); row := all-ones
//   when deg >= q[11] (-> log(1+1e-30) == 0.0f in f32).
//
// Memory-bound expand: 100.7 MB write + 8.4 MB read -> ~17.3 us floor @6.3TB/s.
// Layout: one thread per output float4; 12 % 4 == 0 so each float4 lies inside
// one row -> fully coalesced aligned 16B stores. 3 threads share one deg load.

#define KQ 12
#define LOG_EPS_F (-69.07755278982137f)  // logf(1e-30f)

__global__ __launch_bounds__(256) void dqc_kernel(
    const float* __restrict__ deg_in,
    const float* __restrict__ q,
    float4* __restrict__ out,
    unsigned nvec)
{
    unsigned t = blockIdx.x * 256u + threadIdx.x;
    if (t >= nvec) return;

    unsigned row  = t / 3u;            // magic-mul div by 3
    unsigned part = t - row * 3u;      // 0,1,2 -> which float4 of the row

    float deg = deg_in[row];

    // q is wave-uniform -> compiler emits s_load for these
    float qv[KQ];
#pragma unroll
    for (int i = 0; i < KQ; ++i) qv[i] = q[i];

    // searchsorted(q, deg, 'right') - 1, clipped to [0, KQ-2]
    // = max i in [0,10] with deg >= q[i]  (deg >= q[0]=0 always here)
    int   idx = 0;
    float lo  = qv[0];
    float hi  = qv[1];
#pragma unroll
    for (int i = 1; i <= KQ - 2; ++i) {
        bool ge = (deg >= qv[i]);
        idx = ge ? i : idx;
        lo  = ge ? qv[i]     : lo;
        hi  = ge ? qv[i + 1] : hi;
    }

    float pos = (deg - lo) / (hi - lo + 1e-10f);
    pos = fminf(fmaxf(pos, 0.0f), 1.0f);

    bool in_range = (deg >= qv[0]) && (deg < qv[KQ - 1]);
    bool top      = (deg >= qv[KQ - 1]);   // whole row -> log(1+1e-30) == 0

    float w_lo = in_range ? (1.0f - pos) : 0.0f;
    float w_hi = in_range ? pos          : 0.0f;
    float lw_lo = logf(w_lo + 1e-30f);
    float lw_hi = logf(w_hi + 1e-30f);

    int j0 = (int)part * 4;
    float v[4];
#pragma unroll
    for (int u = 0; u < 4; ++u) {
        int j = j0 + u;
        float x = (j == idx) ? lw_lo : ((j == idx + 1) ? lw_hi : LOG_EPS_F);
        v[u] = top ? 0.0f : x;
    }

    float4 o;
    o.x = v[0]; o.y = v[1]; o.z = v[2]; o.w = v[3];
    out[t] = o;
}

extern "C" void kernel_launch(void* const* d_in, const int* in_sizes, int n_in,
                              void* d_out, int out_size, void* d_ws, size_t ws_size,
                              hipStream_t stream) {
    const float* deg = (const float*)d_in[0];  // (B*S,) flat, 2,097,152
    const float* q   = (const float*)d_in[1];  // (12,)
    float4* out      = (float4*)d_out;         // (B*S*12,) f32, 12%4==0

    unsigned nvec = (unsigned)(out_size / 4);  // float4 count = 6,291,456
    unsigned blocks = (nvec + 255u) / 256u;

    dqc_kernel<<<blocks, 256, 0, stream>>>(deg, q, out, nvec);
}

// Round 2
// 118.858 us; speedup vs baseline: 1.0218x; 1.0218x over previous
//
#include <hip/hip_runtime.h>
#include <math.h>

// DegreeQuantileConverter:
//   deg: (B,S,1) f32, q: (12,) f32 = [0,1,2,4,...,1024]
//   out: (B,S,12) f32 = log(w + 1e-30), w = linear-interp 2-hot row
//   (idx = searchsorted_right(q,deg)-1 clipped to [0,10]); whole row = 0.0f
//   (log(1+1e-30)) when deg >= q[11].
//
// Memory-bound expand: 100.7 MB write + 8.4 MB read -> ~17 us floor @6.3TB/s.
// R1 change: VALU slimming. Precise OCML logf x2 + IEEE fdiv (~150 VALU
// instrs/thread) replaced with v_log_f32 (__logf) and v_rcp_f32 (~80 instrs).
// absmax threshold is 1.38; dominant error (pos near 0 -> steep log) is
// unchanged by the fast paths.
// Layout: one thread per output float4 (12%4==0 -> float4 never crosses a
// row), fully coalesced 16B stores; 3 adjacent lanes share one deg load.

#define KQ 12
#define LOG_EPS_F (-69.07755278982137f)  // logf(1e-30f)

__global__ __launch_bounds__(256) void dqc_kernel(
    const float* __restrict__ deg_in,
    const float* __restrict__ q,
    float4* __restrict__ out,
    unsigned nvec)
{
    unsigned t = blockIdx.x * 256u + threadIdx.x;
    if (t >= nvec) return;

    unsigned row  = t / 3u;            // magic-mul div by 3
    unsigned part = t - row * 3u;      // which float4 of the row (0..2)

    float deg = deg_in[row];

    float qv[KQ];
#pragma unroll
    for (int i = 0; i < KQ; ++i) qv[i] = q[i];

    // searchsorted(q, deg, 'right') - 1, clipped to [0, KQ-2]
    int   idx = 0;
    float lo  = qv[0];
    float hi  = qv[1];
#pragma unroll
    for (int i = 1; i <= KQ - 2; ++i) {
        bool ge = (deg >= qv[i]);
        idx = ge ? i : idx;
        lo  = ge ? qv[i]     : lo;
        hi  = ge ? qv[i + 1] : hi;
    }

    // pos = clamp((deg-lo)/(hi-lo+1e-10), 0, 1) via v_rcp_f32 (1 ulp; divisor
    // is 2^k + 1e-10, so rcp error is negligible vs the 1.38 threshold)
    float pos = (deg - lo) * __builtin_amdgcn_rcpf(hi - lo + 1e-10f);
    pos = fminf(fmaxf(pos, 0.0f), 1.0f);   // v_med3

    bool in_range = (deg >= qv[0]) && (deg < qv[KQ - 1]);
    bool top      = (deg >= qv[KQ - 1]);   // whole row -> log(1+1e-30) == 0.0f

    float w_lo = in_range ? (1.0f - pos) : 0.0f;
    float w_hi = in_range ? pos          : 0.0f;
    // fast log: v_log_f32 (log2) * ln2
    float lw_lo = __logf(w_lo + 1e-30f);
    float lw_hi = __logf(w_hi + 1e-30f);
    float fill  = LOG_EPS_F;
    if (top) { lw_lo = 0.0f; lw_hi = 0.0f; fill = 0.0f; }  // 3 cndmasks

    int j0 = (int)part * 4;
    float v[4];
#pragma unroll
    for (int u = 0; u < 4; ++u) {
        int j = j0 + u;
        v[u] = (j == idx) ? lw_lo : ((j == idx + 1) ? lw_hi : fill);
    }

    float4 o;
    o.x = v[0]; o.y = v[1]; o.z = v[2]; o.w = v[3];
    out[t] = o;
}

extern "C" void kernel_launch(void* const* d_in, const int* in_sizes, int n_in,
                              void* d_out, int out_size, void* d_ws, size_t ws_size,
                              hipStream_t stream) {
    const float* deg = (const float*)d_in[0];  // (B*S,) flat, 2,097,152
    const float* q   = (const float*)d_in[1];  // (12,)
    float4* out      = (float4*)d_out;         // (B*S*12,) f32, 12%4==0

    unsigned nvec = (unsigned)(out_size / 4);  // 6,291,456 float4s
    unsigned blocks = (nvec + 255u) / 256u;

    dqc_kernel<<<blocks, 256, 0, stream>>>(deg, q, out, nvec);
}